// Round 1
// baseline (1216.669 us; speedup 1.0000x reference)
//
#include <hip/hip_runtime.h>
#include <math.h>

// Problem constants (fixed by reference)
#define BB   8
#define LL   512
#define DD   512
#define GG   8
#define SSS  4
#define FGC  4
#define FEC  64
#define EEC  32
#define DHC  256
#define RHC  256
#define NT   (BB*LL)   // 4096 tokens
#define NSLOT 4        // GK*SK = 2*2 active experts per token

__device__ __forceinline__ float gelu_exact(float x) {
    // jax.nn.gelu(approximate=False) = 0.5*x*(1+erf(x/sqrt(2)))
    return 0.5f * x * (1.0f + erff(x * 0.70710678118654752440f));
}

// ---------------------------------------------------------------------------
// Kernel 1: routing. One block per token, 256 threads.
// Computes gating MLP -> group top2 softmax, instance logits -> stage top2
// softmax, emits 4 compact (expert_id, weight) slots. Also zeroes y[t,:].
// All fp32-exact to keep topk selection identical to reference.
// ---------------------------------------------------------------------------
__global__ __launch_bounds__(256) void routing_kernel(
    const float* __restrict__ hidden, const float* __restrict__ feat,
    const float* __restrict__ Wr1, const float* __restrict__ br1,
    const float* __restrict__ Wr2, const float* __restrict__ br2,
    const float* __restrict__ Wfe, const float* __restrict__ bfe,
    const float* __restrict__ Win_h, const float* __restrict__ Win_f,
    const float* __restrict__ bin_b,
    int* __restrict__ sel_e, float* __restrict__ sel_w,
    float* __restrict__ y)
{
    const int t   = blockIdx.x;
    const int tid = threadIdx.x;

    __shared__ float hs[DD];          // hidden row
    __shared__ float gh[RHC];         // gelu(hidden@Wr1+br1)
    __shared__ float femb[GG*FEC];    // feature embedding per group
    __shared__ float part[256];       // reduction scratch
    __shared__ float glog[GG];
    __shared__ float gwv[GG];
    __shared__ float scoreS[GG];
    __shared__ float ilogS[GG*SSS];
    __shared__ float cwv[GG*SSS];

    // zero output row (harness poisons d_out with 0xAA before each call)
    y[t*DD + tid]       = 0.0f;
    y[t*DD + 256 + tid] = 0.0f;

    // load hidden row into LDS
    hs[tid]       = hidden[t*DD + tid];
    hs[tid + 256] = hidden[t*DD + 256 + tid];
    __syncthreads();

    // --- gh[r] = gelu(hidden @ Wr1 + br1), one column per thread ---
    {
        float acc = br1[tid];
        const float* w = Wr1 + tid;          // Wr1[d][tid], stride RHC
        #pragma unroll 4
        for (int d = 0; d < DD; ++d) acc += hs[d] * w[d*RHC];
        gh[tid] = gelu_exact(acc);
    }

    // --- femb[g][e] = feat_g[g,:] @ Wfe[g,:,e] + bfe[g,e]  (512 vals, 2/thread)
    for (int i = tid; i < GG*FEC; i += 256) {
        int g = i >> 6, e = i & 63;
        const float* fg = feat + t*(GG*FGC) + g*FGC;
        const float* wf = Wfe + g*(FGC*FEC) + e;
        float acc = bfe[g*FEC + e];
        acc += fg[0]*wf[0] + fg[1]*wf[FEC] + fg[2]*wf[2*FEC] + fg[3]*wf[3*FEC];
        femb[i] = acc;
    }

    // --- score[g] = mean_f clamp(feat, 0, 1)  (feat is uniform[0,1) -> in01 path)
    if (tid < GG) {
        const float* fg = feat + t*(GG*FGC) + tid*FGC;
        float s = 0.f;
        #pragma unroll
        for (int f = 0; f < FGC; ++f) s += fminf(fmaxf(fg[f], 0.f), 1.f);
        scoreS[tid] = s * 0.25f;
    }
    __syncthreads();

    // --- glog[g] = gh @ Wr2[:,g] + br2[g] : 8 groups x 32 lanes partial ---
    {
        int g = tid >> 5, lane = tid & 31;
        float p = 0.f;
        for (int r = lane; r < RHC; r += 32) p += gh[r] * Wr2[r*GG + g];
        part[tid] = p;
    }
    __syncthreads();
    if (tid < GG) {
        float s = br2[tid];
        #pragma unroll
        for (int l = 0; l < 32; ++l) s += part[tid*32 + l];
        glog[tid] = s;   // TEMP = 1
    }
    __syncthreads();

    // --- ilog partials: 32 (g,s) pairs x 8 sub-lanes ---
    {
        int pair = tid >> 3, sub = tid & 7;
        int g = pair >> 2, s = pair & 3;
        const float* wh = Win_h + g*(DD*SSS) + s;
        float p = 0.f;
        for (int d = sub; d < DD; d += 8) p += hs[d] * wh[d*SSS];
        const float* wf = Win_f + g*(FEC*SSS) + s;
        const float* fe = femb + g*FEC;
        for (int e = sub; e < FEC; e += 8) p += fe[e] * wf[e*SSS];
        part[tid] = p;
    }
    // thread 0: group top-2 softmax (matches _topk_softmax tie semantics)
    if (tid == 0) {
        float a = -INFINITY, b = -INFINITY;
        #pragma unroll
        for (int g = 0; g < GG; ++g) {
            float v = glog[g];
            if (v > a) { b = a; a = v; } else if (v > b) { b = v; }
        }
        float thresh = b, m = a, sum = 0.f;
        float ex[GG];
        #pragma unroll
        for (int g = 0; g < GG; ++g) {
            float v = glog[g];
            ex[g] = (v >= thresh) ? __expf(v - m) : 0.f;
            sum += ex[g];
        }
        float inv = 1.0f / sum;
        #pragma unroll
        for (int g = 0; g < GG; ++g) gwv[g] = ex[g] * inv;
    }
    __syncthreads();

    // finalize ilog (+ bin_b + BIAS*rule, TEMP=1, BIAS=1, SHARP=16)
    if (tid < GG*SSS) {
        int g = tid >> 2, s = tid & 3;
        const float centers[4] = {0.0f, 1.0f/3.0f, 2.0f/3.0f, 1.0f};
        float sum8 = 0.f;
        #pragma unroll
        for (int i = 0; i < 8; ++i) sum8 += part[tid*8 + i];
        float d = scoreS[g] - centers[s];
        ilogS[tid] = sum8 + bin_b[tid] - 16.0f * d * d;
    }
    __syncthreads();

    // per-group stage top-2 softmax
    if (tid < GG) {
        float v0 = ilogS[tid*4+0], v1 = ilogS[tid*4+1];
        float v2 = ilogS[tid*4+2], v3 = ilogS[tid*4+3];
        float a = -INFINITY, b = -INFINITY;
        float vv[4] = {v0, v1, v2, v3};
        #pragma unroll
        for (int s = 0; s < 4; ++s) {
            float v = vv[s];
            if (v > a) { b = a; a = v; } else if (v > b) { b = v; }
        }
        float thresh = b, m = a, sum = 0.f;
        float ex[4];
        #pragma unroll
        for (int s = 0; s < 4; ++s) {
            ex[s] = (vv[s] >= thresh) ? __expf(vv[s] - m) : 0.f;
            sum += ex[s];
        }
        float inv = 1.0f / sum;
        #pragma unroll
        for (int s = 0; s < 4; ++s) cwv[tid*4 + s] = ex[s] * inv;
    }
    __syncthreads();

    // thread 0: build compact slot list (generically exactly 4 nonzeros)
    if (tid == 0) {
        int slot = 0;
        for (int g = 0; g < GG && slot < NSLOT; ++g) {
            if (gwv[g] > 0.f) {
                for (int s = 0; s < SSS && slot < NSLOT; ++s) {
                    float w = gwv[g] * cwv[g*4 + s];
                    if (w > 0.f) {
                        sel_e[t*NSLOT + slot] = g*SSS + s;
                        sel_w[t*NSLOT + slot] = w;
                        ++slot;
                    }
                }
            }
        }
        for (; slot < NSLOT; ++slot) {
            sel_e[t*NSLOT + slot] = 0;
            sel_w[t*NSLOT + slot] = 0.f;
        }
    }
}

// ---------------------------------------------------------------------------
// Kernel 2: expert compute. One block per (token, slot).
// y[t,:] += w * ( gelu(hidden[t] @ We1[e] + be1[e]) @ We2[e] + be2[e] )
// ---------------------------------------------------------------------------
__global__ __launch_bounds__(256) void expert_kernel(
    const float* __restrict__ hidden,
    const float* __restrict__ We1, const float* __restrict__ be1,
    const float* __restrict__ We2, const float* __restrict__ be2,
    const int* __restrict__ sel_e, const float* __restrict__ sel_w,
    float* __restrict__ y)
{
    const int t    = blockIdx.x;
    const int slot = blockIdx.y;
    const float wv = sel_w[t*NSLOT + slot];
    if (wv == 0.f) return;                 // uniform across block
    const int e   = sel_e[t*NSLOT + slot];
    const int tid = threadIdx.x;

    __shared__ float hs[DD];
    __shared__ float h1[DHC];

    hs[tid]       = hidden[t*DD + tid];
    hs[tid + 256] = hidden[t*DD + 256 + tid];
    __syncthreads();

    // phase 1: h1[h] = gelu(hidden . We1[e,:,h] + be1[e,h])
    {
        float acc = be1[e*DHC + tid];
        const float* w1 = We1 + (size_t)e*(DD*DHC) + tid;   // stride DHC over d
        #pragma unroll 4
        for (int d = 0; d < DD; ++d) acc += hs[d] * w1[d*DHC];
        h1[tid] = gelu_exact(acc);
    }
    __syncthreads();

    // phase 2: y[t,j] += wv * (h1 . We2[e,:,j] + be2[e,j]),  j = tid, tid+256
    {
        float acc0 = 0.f, acc1 = 0.f;
        const float* w2 = We2 + (size_t)e*(DHC*DD);
        #pragma unroll 4
        for (int h = 0; h < DHC; ++h) {
            float hv = h1[h];
            acc0 += hv * w2[h*DD + tid];
            acc1 += hv * w2[h*DD + 256 + tid];
        }
        atomicAdd(&y[t*DD + tid],       wv * (acc0 + be2[e*DD + tid]));
        atomicAdd(&y[t*DD + 256 + tid], wv * (acc1 + be2[e*DD + 256 + tid]));
    }
}

extern "C" void kernel_launch(void* const* d_in, const int* in_sizes, int n_in,
                              void* d_out, int out_size, void* d_ws, size_t ws_size,
                              hipStream_t stream) {
    const float* hidden = (const float*)d_in[0];
    const float* feat   = (const float*)d_in[1];
    // d_in[2] = valid_mask (unused by reference)
    const float* Wr1    = (const float*)d_in[3];
    const float* br1    = (const float*)d_in[4];
    const float* Wr2    = (const float*)d_in[5];
    const float* br2    = (const float*)d_in[6];
    const float* Wfe    = (const float*)d_in[7];
    const float* bfe    = (const float*)d_in[8];
    const float* Win_h  = (const float*)d_in[9];
    const float* Win_f  = (const float*)d_in[10];
    const float* bin_b  = (const float*)d_in[11];
    const float* We1    = (const float*)d_in[12];
    const float* be1    = (const float*)d_in[13];
    const float* We2    = (const float*)d_in[14];
    const float* be2    = (const float*)d_in[15];
    float* y = (float*)d_out;

    int*   sel_e = (int*)d_ws;
    float* sel_w = (float*)((char*)d_ws + (size_t)NT*NSLOT*sizeof(int));

    routing_kernel<<<NT, 256, 0, stream>>>(hidden, feat, Wr1, br1, Wr2, br2,
                                           Wfe, bfe, Win_h, Win_f, bin_b,
                                           sel_e, sel_w, y);
    dim3 grid(NT, NSLOT);
    expert_kernel<<<grid, 256, 0, stream>>>(hidden, We1, be1, We2, be2,
                                            sel_e, sel_w, y);
}

// Round 2
// 965.048 us; speedup vs baseline: 1.2607x; 1.2607x over previous
//
#include <hip/hip_runtime.h>
#include <math.h>

// Problem constants (fixed by reference)
#define BB   8
#define LL   512
#define DD   512
#define GG   8
#define SSS  4
#define FGC  4
#define FEC  64
#define EEC  32
#define DHC  256
#define RHC  256
#define NT   (BB*LL)   // 4096 tokens
#define TM   32        // tokens per expert-GEMM tile

__device__ __forceinline__ float gelu_exact(float x) {
    return 0.5f * x * (1.0f + erff(x * 0.70710678118654752440f));
}

// ---------------------------------------------------------------------------
// Kernel 1: routing. One block per token, 256 threads. fp32-exact topk.
// Appends (token, weight) to per-expert buckets; zeroes y row.
// ---------------------------------------------------------------------------
__global__ __launch_bounds__(256) void routing_kernel(
    const float* __restrict__ hidden, const float* __restrict__ feat,
    const float* __restrict__ Wr1, const float* __restrict__ br1,
    const float* __restrict__ Wr2, const float* __restrict__ br2,
    const float* __restrict__ Wfe, const float* __restrict__ bfe,
    const float* __restrict__ Win_h, const float* __restrict__ Win_f,
    const float* __restrict__ bin_b,
    int* __restrict__ bucket_tok, float* __restrict__ bucket_w,
    int* __restrict__ counts,
    float* __restrict__ y)
{
    const int t   = blockIdx.x;
    const int tid = threadIdx.x;

    __shared__ float hs[DD];
    __shared__ float gh[RHC];
    __shared__ float femb[GG*FEC];
    __shared__ float part[256];
    __shared__ float glog[GG];
    __shared__ float gwv[GG];
    __shared__ float scoreS[GG];
    __shared__ float ilogS[GG*SSS];
    __shared__ float cwv[GG*SSS];

    // zero output row (harness poisons d_out)
    y[t*DD + tid]       = 0.0f;
    y[t*DD + 256 + tid] = 0.0f;

    hs[tid]       = hidden[t*DD + tid];
    hs[tid + 256] = hidden[t*DD + 256 + tid];
    __syncthreads();

    // gh = gelu(hidden @ Wr1 + br1)
    {
        float acc = br1[tid];
        const float* w = Wr1 + tid;
        #pragma unroll 4
        for (int d = 0; d < DD; ++d) acc += hs[d] * w[d*RHC];
        gh[tid] = gelu_exact(acc);
    }

    // femb
    for (int i = tid; i < GG*FEC; i += 256) {
        int g = i >> 6, e = i & 63;
        const float* fg = feat + t*(GG*FGC) + g*FGC;
        const float* wf = Wfe + g*(FGC*FEC) + e;
        float acc = bfe[g*FEC + e];
        acc += fg[0]*wf[0] + fg[1]*wf[FEC] + fg[2]*wf[2*FEC] + fg[3]*wf[3*FEC];
        femb[i] = acc;
    }

    if (tid < GG) {
        const float* fg = feat + t*(GG*FGC) + tid*FGC;
        float s = 0.f;
        #pragma unroll
        for (int f = 0; f < FGC; ++f) s += fminf(fmaxf(fg[f], 0.f), 1.f);
        scoreS[tid] = s * 0.25f;
    }
    __syncthreads();

    // glog
    {
        int g = tid >> 5, lane = tid & 31;
        float p = 0.f;
        for (int r = lane; r < RHC; r += 32) p += gh[r] * Wr2[r*GG + g];
        part[tid] = p;
    }
    __syncthreads();
    if (tid < GG) {
        float s = br2[tid];
        #pragma unroll
        for (int l = 0; l < 32; ++l) s += part[tid*32 + l];
        glog[tid] = s;
    }
    __syncthreads();

    // ilog partials
    {
        int pair = tid >> 3, sub = tid & 7;
        int g = pair >> 2, s = pair & 3;
        const float* wh = Win_h + g*(DD*SSS) + s;
        float p = 0.f;
        for (int d = sub; d < DD; d += 8) p += hs[d] * wh[d*SSS];
        const float* wf = Win_f + g*(FEC*SSS) + s;
        const float* fe = femb + g*FEC;
        for (int e = sub; e < FEC; e += 8) p += fe[e] * wf[e*SSS];
        part[tid] = p;
    }
    if (tid == 0) {
        float a = -INFINITY, b = -INFINITY;
        #pragma unroll
        for (int g = 0; g < GG; ++g) {
            float v = glog[g];
            if (v > a) { b = a; a = v; } else if (v > b) { b = v; }
        }
        float thresh = b, m = a, sum = 0.f;
        float ex[GG];
        #pragma unroll
        for (int g = 0; g < GG; ++g) {
            float v = glog[g];
            ex[g] = (v >= thresh) ? __expf(v - m) : 0.f;
            sum += ex[g];
        }
        float inv = 1.0f / sum;
        #pragma unroll
        for (int g = 0; g < GG; ++g) gwv[g] = ex[g] * inv;
    }
    __syncthreads();

    if (tid < GG*SSS) {
        int g = tid >> 2, s = tid & 3;
        const float centers[4] = {0.0f, 1.0f/3.0f, 2.0f/3.0f, 1.0f};
        float sum8 = 0.f;
        #pragma unroll
        for (int i = 0; i < 8; ++i) sum8 += part[tid*8 + i];
        float d = scoreS[g] - centers[s];
        ilogS[tid] = sum8 + bin_b[tid] - 16.0f * d * d;
    }
    __syncthreads();

    if (tid < GG) {
        float vv[4] = {ilogS[tid*4+0], ilogS[tid*4+1], ilogS[tid*4+2], ilogS[tid*4+3]};
        float a = -INFINITY, b = -INFINITY;
        #pragma unroll
        for (int s = 0; s < 4; ++s) {
            float v = vv[s];
            if (v > a) { b = a; a = v; } else if (v > b) { b = v; }
        }
        float thresh = b, m = a, sum = 0.f;
        float ex[4];
        #pragma unroll
        for (int s = 0; s < 4; ++s) {
            ex[s] = (vv[s] >= thresh) ? __expf(vv[s] - m) : 0.f;
            sum += ex[s];
        }
        float inv = 1.0f / sum;
        #pragma unroll
        for (int s = 0; s < 4; ++s) cwv[tid*4 + s] = ex[s] * inv;
    }
    __syncthreads();

    // append to per-expert buckets (handles >4 slots on exact ties, like ref)
    if (tid == 0) {
        for (int g = 0; g < GG; ++g) {
            float gw = gwv[g];
            if (gw > 0.f) {
                for (int s = 0; s < SSS; ++s) {
                    float w = gw * cwv[g*4 + s];
                    if (w > 0.f) {
                        int ee = g*SSS + s;
                        int pos = atomicAdd(&counts[ee], 1);
                        bucket_tok[ee*NT + pos] = t;
                        bucket_w[ee*NT + pos]   = w;
                    }
                }
            }
        }
    }
}

// ---------------------------------------------------------------------------
// Kernel 2: expert-batched GEMM. Block = (expert e, tile of TM tokens).
// phase1: H = gelu(X @ We1 + be1)  (TM x 256, via register tile 2x16/thread)
// phase2: Y = w * (H @ We2 + be2)  (TM x 512, register tile 2x32/thread)
// ---------------------------------------------------------------------------
__global__ __launch_bounds__(256) void expert_gemm(
    const float* __restrict__ hidden,
    const float* __restrict__ We1, const float* __restrict__ be1,
    const float* __restrict__ We2, const float* __restrict__ be2,
    const int* __restrict__ bucket_tok, const float* __restrict__ bucket_w,
    const int* __restrict__ counts,
    float* __restrict__ y)
{
    const int e   = blockIdx.y;
    const int cnt = counts[e];
    const int r0  = blockIdx.x * TM;
    if (r0 >= cnt) return;
    const int nrow = min(TM, cnt - r0);
    const int tid = threadIdx.x;
    const int tx = tid & 15, ty = tid >> 4;
    const int rA = ty*2, rB = ty*2 + 1;

    __shared__ float Xs[TM][68];        // 64-wide K chunk, +4 pad
    __shared__ float Hs[TM][DHC+4];     // phase-2 input, +4 pad
    __shared__ int   toks[TM];
    __shared__ float tws[TM];

    if (tid < TM) {
        if (tid < nrow) {
            toks[tid] = bucket_tok[e*NT + r0 + tid];
            tws[tid]  = bucket_w[e*NT + r0 + tid];
        } else { toks[tid] = -1; tws[tid] = 0.f; }
    }

    // ---- phase 1: acc[2][16], cols = tx*4 + jj*64 + m ----
    float acc0[16], acc1[16];
    #pragma unroll
    for (int j = 0; j < 16; ++j) { acc0[j] = 0.f; acc1[j] = 0.f; }
    const float* W1 = We1 + (size_t)e*(DD*DHC);

    for (int kc = 0; kc < DD; kc += 64) {
        __syncthreads();   // Xs reuse barrier (also covers toks on first iter)
        for (int i = tid; i < TM*16; i += 256) {
            int r = i >> 4, q = i & 15;
            int tk = toks[r];
            float4 v = make_float4(0.f, 0.f, 0.f, 0.f);
            if (tk >= 0) v = *(const float4*)(hidden + (size_t)tk*DD + kc + q*4);
            *(float4*)(&Xs[r][q*4]) = v;
        }
        __syncthreads();
        #pragma unroll 4
        for (int k = 0; k < 64; ++k) {
            float a0 = Xs[rA][k], a1 = Xs[rB][k];
            const float* wrow = W1 + (size_t)(kc + k)*DHC + tx*4;
            #pragma unroll
            for (int jj = 0; jj < 4; ++jj) {
                float4 w = *(const float4*)(wrow + jj*64);
                acc0[jj*4+0] += a0*w.x; acc0[jj*4+1] += a0*w.y;
                acc0[jj*4+2] += a0*w.z; acc0[jj*4+3] += a0*w.w;
                acc1[jj*4+0] += a1*w.x; acc1[jj*4+1] += a1*w.y;
                acc1[jj*4+2] += a1*w.z; acc1[jj*4+3] += a1*w.w;
            }
        }
    }

    // bias + gelu -> Hs
    #pragma unroll
    for (int jj = 0; jj < 4; ++jj) {
        #pragma unroll
        for (int m = 0; m < 4; ++m) {
            int col = tx*4 + jj*64 + m;
            float b = be1[e*DHC + col];
            Hs[rA][col] = gelu_exact(acc0[jj*4+m] + b);
            Hs[rB][col] = gelu_exact(acc1[jj*4+m] + b);
        }
    }
    __syncthreads();

    // ---- phase 2: c[2][32], cols = tx*4 + jj*64 + m, jj=0..7 ----
    float c0[32], c1[32];
    #pragma unroll
    for (int j = 0; j < 32; ++j) { c0[j] = 0.f; c1[j] = 0.f; }
    const float* W2 = We2 + (size_t)e*(DHC*DD);

    #pragma unroll 2
    for (int k = 0; k < DHC; ++k) {
        float a0 = Hs[rA][k], a1 = Hs[rB][k];
        const float* wrow = W2 + (size_t)k*DD + tx*4;
        #pragma unroll
        for (int jj = 0; jj < 8; ++jj) {
            float4 w = *(const float4*)(wrow + jj*64);
            c0[jj*4+0] += a0*w.x; c0[jj*4+1] += a0*w.y;
            c0[jj*4+2] += a0*w.z; c0[jj*4+3] += a0*w.w;
            c1[jj*4+0] += a1*w.x; c1[jj*4+1] += a1*w.y;
            c1[jj*4+2] += a1*w.z; c1[jj*4+3] += a1*w.w;
        }
    }

    // epilogue: weighted atomicAdd into y (+ be2 fused, weighted)
    const int tkA = toks[rA], tkB = toks[rB];
    const float wA = tws[rA], wB = tws[rB];
    #pragma unroll
    for (int jj = 0; jj < 8; ++jj) {
        #pragma unroll
        for (int m = 0; m < 4; ++m) {
            int col = tx*4 + jj*64 + m;
            float b2 = be2[e*DD + col];
            if (tkA >= 0) atomicAdd(&y[(size_t)tkA*DD + col], wA*(c0[jj*4+m] + b2));
            if (tkB >= 0) atomicAdd(&y[(size_t)tkB*DD + col], wB*(c1[jj*4+m] + b2));
        }
    }
}

extern "C" void kernel_launch(void* const* d_in, const int* in_sizes, int n_in,
                              void* d_out, int out_size, void* d_ws, size_t ws_size,
                              hipStream_t stream) {
    const float* hidden = (const float*)d_in[0];
    const float* feat   = (const float*)d_in[1];
    // d_in[2] = valid_mask (unused)
    const float* Wr1    = (const float*)d_in[3];
    const float* br1    = (const float*)d_in[4];
    const float* Wr2    = (const float*)d_in[5];
    const float* br2    = (const float*)d_in[6];
    const float* Wfe    = (const float*)d_in[7];
    const float* bfe    = (const float*)d_in[8];
    const float* Win_h  = (const float*)d_in[9];
    const float* Win_f  = (const float*)d_in[10];
    const float* bin_b  = (const float*)d_in[11];
    const float* We1    = (const float*)d_in[12];
    const float* be1    = (const float*)d_in[13];
    const float* We2    = (const float*)d_in[14];
    const float* be2    = (const float*)d_in[15];
    float* y = (float*)d_out;

    char* ws = (char*)d_ws;
    int*   bucket_tok = (int*)ws;                                   ws += (size_t)EEC*NT*sizeof(int);
    float* bucket_w   = (float*)ws;                                 ws += (size_t)EEC*NT*sizeof(float);
    int*   counts     = (int*)ws;

    hipMemsetAsync(counts, 0, EEC*sizeof(int), stream);

    routing_kernel<<<NT, 256, 0, stream>>>(hidden, feat, Wr1, br1, Wr2, br2,
                                           Wfe, bfe, Win_h, Win_f, bin_b,
                                           bucket_tok, bucket_w, counts, y);

    dim3 grid2((NT + TM - 1)/TM, EEC);
    expert_gemm<<<grid2, 256, 0, stream>>>(hidden, We1, be1, We2, be2,
                                           bucket_tok, bucket_w, counts, y);
}

// Round 4
// 503.245 us; speedup vs baseline: 2.4177x; 1.9177x over previous
//
#include <hip/hip_runtime.h>
#include <math.h>

// Problem constants (fixed by reference)
#define BB   8
#define LL   512
#define DD   512
#define GG   8
#define SSS  4
#define FGC  4
#define FEC  64
#define EEC  32
#define DHC  256
#define RHC  256
#define NT   (BB*LL)   // 4096 tokens
#define TM   32        // tokens per expert-GEMM tile

#define XC_STRIDE 264  // shorts per k8 group in Xc (32*8 + 8 pad)
#define HP_STRIDE 272  // shorts per h8 group in Hp (32*8 + 16 pad)

typedef __attribute__((ext_vector_type(8))) short short8;
typedef __attribute__((ext_vector_type(4))) float floatx4;

__device__ __forceinline__ float gelu_exact(float x) {
    return 0.5f * x * (1.0f + erff(x * 0.70710678118654752440f));
}

__device__ __forceinline__ short bf16_rne(float f) {
    union { float f; unsigned u; } a; a.f = f;
    unsigned u = a.u;
    return (short)((u + 0x7fffu + ((u >> 16) & 1u)) >> 16);
}

__device__ __forceinline__ floatx4 mfma16(short8 a, short8 b, floatx4 c) {
    return __builtin_amdgcn_mfma_f32_16x16x32_bf16(a, b, c, 0, 0, 0);
}

// ---------------------------------------------------------------------------
// Kernel 1: routing (byte-identical to the round-2 passing version).
// fp32-exact topk; appends (token, weight) to per-expert buckets; zeroes y.
// ---------------------------------------------------------------------------
__global__ __launch_bounds__(256) void routing_kernel(
    const float* __restrict__ hidden, const float* __restrict__ feat,
    const float* __restrict__ Wr1, const float* __restrict__ br1,
    const float* __restrict__ Wr2, const float* __restrict__ br2,
    const float* __restrict__ Wfe, const float* __restrict__ bfe,
    const float* __restrict__ Win_h, const float* __restrict__ Win_f,
    const float* __restrict__ bin_b,
    int* __restrict__ bucket_tok, float* __restrict__ bucket_w,
    int* __restrict__ counts,
    float* __restrict__ y)
{
    const int t   = blockIdx.x;
    const int tid = threadIdx.x;

    __shared__ float hs[DD];
    __shared__ float gh[RHC];
    __shared__ float femb[GG*FEC];
    __shared__ float part[256];
    __shared__ float glog[GG];
    __shared__ float gwv[GG];
    __shared__ float scoreS[GG];
    __shared__ float ilogS[GG*SSS];
    __shared__ float cwv[GG*SSS];

    y[t*DD + tid]       = 0.0f;
    y[t*DD + 256 + tid] = 0.0f;

    hs[tid]       = hidden[t*DD + tid];
    hs[tid + 256] = hidden[t*DD + 256 + tid];
    __syncthreads();

    {
        float acc = br1[tid];
        const float* w = Wr1 + tid;
        #pragma unroll 4
        for (int d = 0; d < DD; ++d) acc += hs[d] * w[d*RHC];
        gh[tid] = gelu_exact(acc);
    }

    for (int i = tid; i < GG*FEC; i += 256) {
        int g = i >> 6, e = i & 63;
        const float* fg = feat + t*(GG*FGC) + g*FGC;
        const float* wf = Wfe + g*(FGC*FEC) + e;
        float acc = bfe[g*FEC + e];
        acc += fg[0]*wf[0] + fg[1]*wf[FEC] + fg[2]*wf[2*FEC] + fg[3]*wf[3*FEC];
        femb[i] = acc;
    }

    if (tid < GG) {
        const float* fg = feat + t*(GG*FGC) + tid*FGC;
        float s = 0.f;
        #pragma unroll
        for (int f = 0; f < FGC; ++f) s += fminf(fmaxf(fg[f], 0.f), 1.f);
        scoreS[tid] = s * 0.25f;
    }
    __syncthreads();

    {
        int g = tid >> 5, lane = tid & 31;
        float p = 0.f;
        for (int r = lane; r < RHC; r += 32) p += gh[r] * Wr2[r*GG + g];
        part[tid] = p;
    }
    __syncthreads();
    if (tid < GG) {
        float s = br2[tid];
        #pragma unroll
        for (int l = 0; l < 32; ++l) s += part[tid*32 + l];
        glog[tid] = s;
    }
    __syncthreads();

    {
        int pair = tid >> 3, sub = tid & 7;
        int g = pair >> 2, s = pair & 3;
        const float* wh = Win_h + g*(DD*SSS) + s;
        float p = 0.f;
        for (int d = sub; d < DD; d += 8) p += hs[d] * wh[d*SSS];
        const float* wf = Win_f + g*(FEC*SSS) + s;
        const float* fe = femb + g*FEC;
        for (int e = sub; e < FEC; e += 8) p += fe[e] * wf[e*SSS];
        part[tid] = p;
    }
    if (tid == 0) {
        float a = -INFINITY, b = -INFINITY;
        #pragma unroll
        for (int g = 0; g < GG; ++g) {
            float v = glog[g];
            if (v > a) { b = a; a = v; } else if (v > b) { b = v; }
        }
        float thresh = b, m = a, sum = 0.f;
        float ex[GG];
        #pragma unroll
        for (int g = 0; g < GG; ++g) {
            float v = glog[g];
            ex[g] = (v >= thresh) ? __expf(v - m) : 0.f;
            sum += ex[g];
        }
        float inv = 1.0f / sum;
        #pragma unroll
        for (int g = 0; g < GG; ++g) gwv[g] = ex[g] * inv;
    }
    __syncthreads();

    if (tid < GG*SSS) {
        int g = tid >> 2, s = tid & 3;
        const float centers[4] = {0.0f, 1.0f/3.0f, 2.0f/3.0f, 1.0f};
        float sum8 = 0.f;
        #pragma unroll
        for (int i = 0; i < 8; ++i) sum8 += part[tid*8 + i];
        float d = scoreS[g] - centers[s];
        ilogS[tid] = sum8 + bin_b[tid] - 16.0f * d * d;
    }
    __syncthreads();

    if (tid < GG) {
        float vv[4] = {ilogS[tid*4+0], ilogS[tid*4+1], ilogS[tid*4+2], ilogS[tid*4+3]};
        float a = -INFINITY, b = -INFINITY;
        #pragma unroll
        for (int s = 0; s < 4; ++s) {
            float v = vv[s];
            if (v > a) { b = a; a = v; } else if (v > b) { b = v; }
        }
        float thresh = b, m = a, sum = 0.f;
        float ex[4];
        #pragma unroll
        for (int s = 0; s < 4; ++s) {
            ex[s] = (vv[s] >= thresh) ? __expf(vv[s] - m) : 0.f;
            sum += ex[s];
        }
        float inv = 1.0f / sum;
        #pragma unroll
        for (int s = 0; s < 4; ++s) cwv[tid*4 + s] = ex[s] * inv;
    }
    __syncthreads();

    if (tid == 0) {
        for (int g = 0; g < GG; ++g) {
            float gw = gwv[g];
            if (gw > 0.f) {
                for (int s = 0; s < SSS; ++s) {
                    float w = gw * cwv[g*4 + s];
                    if (w > 0.f) {
                        int ee = g*SSS + s;
                        int pos = atomicAdd(&counts[ee], 1);
                        bucket_tok[ee*NT + pos] = t;
                        bucket_w[ee*NT + pos]   = w;
                    }
                }
            }
        }
    }
}

// ---------------------------------------------------------------------------
// Kernel 2: bf16 MFMA expert GEMM with in-kernel fp32->bf16 LDS staging.
// Block = (expert, 32-token tile), 4 waves.
// phase1: H = gelu(X @ We1 + be1); wave owns 32x64 of (32x256), K=512
// phase2: Y += w*(H @ We2 + be2); wave owns 32x128 of (32x512), K=256
// A-frag: m=lane&15, k=quad*8+j  (LDS [k8][m][8])
// B-frag: n=lane&15, k=quad*8+j  (LDS [k8][n][8])
// C/D:    col=lane&15, row=quad*4+reg
// ---------------------------------------------------------------------------
__global__ __launch_bounds__(256) void expert_mfma(
    const float* __restrict__ hidden,
    const float* __restrict__ We1, const float* __restrict__ be1,
    const float* __restrict__ We2, const float* __restrict__ be2,
    const int* __restrict__ bucket_tok, const float* __restrict__ bucket_w,
    const int* __restrict__ counts,
    float* __restrict__ y)
{
    const int e   = blockIdx.y;
    const int cnt = counts[e];
    const int r0  = blockIdx.x * TM;
    if (r0 >= cnt) return;
    const int nrow = min(TM, cnt - r0);
    const int tid  = threadIdx.x;
    const int wave = tid >> 6;
    const int lane = tid & 63;
    const int lm   = lane & 15;
    const int quad = lane >> 4;

    __shared__ short Xc[8 * XC_STRIDE];    // X chunk, [k8 local][m][8]
    __shared__ short Bs[16384];            // W chunk: ph1 [8][256][8] / ph2 [4][512][8]
    __shared__ short Hp[32 * HP_STRIDE];   // H, [h8][m][8]
    __shared__ int   toks[TM];
    __shared__ float tws[TM];

    if (tid < TM) {
        if (tid < nrow) {
            toks[tid] = bucket_tok[e*NT + r0 + tid];
            tws[tid]  = bucket_w[e*NT + r0 + tid];
        } else { toks[tid] = -1; tws[tid] = 0.f; }
    }
    __syncthreads();

    // ---- phase 1 ----
    floatx4 acc[2][4];
    #pragma unroll
    for (int mb = 0; mb < 2; ++mb)
        #pragma unroll
        for (int nb = 0; nb < 4; ++nb)
            acc[mb][nb] = (floatx4){0.f, 0.f, 0.f, 0.f};

    const float* W1 = We1 + (size_t)e * DD * DHC;    // [k][n], n stride DHC
    const int xr = tid & 31;     // token row for X staging
    const int xc = tid >> 5;     // k8 group 0..7

    for (int kc = 0; kc < DD; kc += 64) {
        __syncthreads();   // protect Xc/Bs from previous iteration's reads
        // stage X chunk: thread (xr, xc) -> hidden[toks[xr]][kc + xc*8 .. +7]
        {
            const int tk = toks[xr];
            float4 v0 = make_float4(0.f,0.f,0.f,0.f), v1 = v0;
            if (tk >= 0) {
                const float* src = hidden + (size_t)tk*DD + kc + xc*8;
                v0 = *(const float4*)src;
                v1 = *(const float4*)(src + 4);
            }
            short8 xv;
            xv[0]=bf16_rne(v0.x); xv[1]=bf16_rne(v0.y); xv[2]=bf16_rne(v0.z); xv[3]=bf16_rne(v0.w);
            xv[4]=bf16_rne(v1.x); xv[5]=bf16_rne(v1.y); xv[6]=bf16_rne(v1.z); xv[7]=bf16_rne(v1.w);
            *(short8*)(&Xc[xc * XC_STRIDE + xr * 8]) = xv;
        }
        // stage W1 chunk: thread n = tid; k8g 0..7; coalesced row reads
        #pragma unroll
        for (int k8g = 0; k8g < 8; ++k8g) {
            const float* src = W1 + (size_t)(kc + k8g*8)*DHC + tid;
            short8 bv;
            #pragma unroll
            for (int j = 0; j < 8; ++j) bv[j] = bf16_rne(src[(size_t)j*DHC]);
            *(short8*)(&Bs[(k8g*256 + tid) * 8]) = bv;
        }
        __syncthreads();
        #pragma unroll
        for (int kk = 0; kk < 64; kk += 32) {
            const int k8l = (kk >> 3) + quad;
            short8 a0 = *(const short8*)(&Xc[k8l * XC_STRIDE + lm * 8]);
            short8 a1 = *(const short8*)(&Xc[k8l * XC_STRIDE + (16 + lm) * 8]);
            #pragma unroll
            for (int nb = 0; nb < 4; ++nb) {
                const int n = wave*64 + nb*16 + lm;
                short8 b = *(const short8*)(&Bs[(k8l*256 + n) * 8]);
                acc[0][nb] = mfma16(a0, b, acc[0][nb]);
                acc[1][nb] = mfma16(a1, b, acc[1][nb]);
            }
        }
    }

    // bias + gelu -> Hp (bf16, A-layout for phase 2); waves write disjoint h
    #pragma unroll
    for (int nb = 0; nb < 4; ++nb) {
        const int h = wave*64 + nb*16 + lm;
        const float b1 = be1[e*DHC + h];
        #pragma unroll
        for (int mb = 0; mb < 2; ++mb) {
            #pragma unroll
            for (int r = 0; r < 4; ++r) {
                const int m = mb*16 + quad*4 + r;
                Hp[(h >> 3) * HP_STRIDE + m * 8 + (h & 7)] =
                    bf16_rne(gelu_exact(acc[mb][nb][r] + b1));
            }
        }
    }

    // ---- phase 2 ----
    floatx4 c[2][8];
    #pragma unroll
    for (int mb = 0; mb < 2; ++mb)
        #pragma unroll
        for (int nb = 0; nb < 8; ++nb)
            c[mb][nb] = (floatx4){0.f, 0.f, 0.f, 0.f};

    const float* W2 = We2 + (size_t)e * DHC * DD;    // [k][n], n stride DD

    for (int kc = 0; kc < DHC; kc += 32) {
        __syncthreads();   // Bs reuse barrier; first iter also fences Hp writes
        // stage W2 chunk: [4 k8][512 n][8]; thread covers n=tid and n=tid+256
        #pragma unroll
        for (int k8g = 0; k8g < 4; ++k8g) {
            #pragma unroll
            for (int half = 0; half < 2; ++half) {
                const int n = half*256 + tid;
                const float* src = W2 + (size_t)(kc + k8g*8)*DD + n;
                short8 bv;
                #pragma unroll
                for (int j = 0; j < 8; ++j) bv[j] = bf16_rne(src[(size_t)j*DD]);
                *(short8*)(&Bs[(k8g*512 + n) * 8]) = bv;
            }
        }
        __syncthreads();
        const int k8 = (kc >> 3) + quad;   // global h8 index into Hp
        short8 a0 = *(const short8*)(&Hp[k8 * HP_STRIDE + lm * 8]);
        short8 a1 = *(const short8*)(&Hp[k8 * HP_STRIDE + (16 + lm) * 8]);
        #pragma unroll
        for (int nb = 0; nb < 8; ++nb) {
            const int n = wave*128 + nb*16 + lm;
            short8 b = *(const short8*)(&Bs[(quad*512 + n) * 8]);
            c[0][nb] = mfma16(a0, b, c[0][nb]);
            c[1][nb] = mfma16(a1, b, c[1][nb]);
        }
    }

    // epilogue: weighted atomicAdd into y (+ be2)
    #pragma unroll
    for (int nb = 0; nb < 8; ++nb) {
        const int col = wave*128 + nb*16 + lm;
        const float b2 = be2[e*DD + col];
        #pragma unroll
        for (int mb = 0; mb < 2; ++mb) {
            #pragma unroll
            for (int r = 0; r < 4; ++r) {
                const int m = mb*16 + quad*4 + r;
                const int tk = toks[m];
                if (tk >= 0)
                    atomicAdd(&y[(size_t)tk*DD + col], tws[m] * (c[mb][nb][r] + b2));
            }
        }
    }
}

extern "C" void kernel_launch(void* const* d_in, const int* in_sizes, int n_in,
                              void* d_out, int out_size, void* d_ws, size_t ws_size,
                              hipStream_t stream) {
    const float* hidden = (const float*)d_in[0];
    const float* feat   = (const float*)d_in[1];
    // d_in[2] = valid_mask (unused)
    const float* Wr1    = (const float*)d_in[3];
    const float* br1    = (const float*)d_in[4];
    const float* Wr2    = (const float*)d_in[5];
    const float* br2    = (const float*)d_in[6];
    const float* Wfe    = (const float*)d_in[7];
    const float* bfe    = (const float*)d_in[8];
    const float* Win_h  = (const float*)d_in[9];
    const float* Win_f  = (const float*)d_in[10];
    const float* bin_b  = (const float*)d_in[11];
    const float* We1    = (const float*)d_in[12];
    const float* be1    = (const float*)d_in[13];
    const float* We2    = (const float*)d_in[14];
    const float* be2    = (const float*)d_in[15];
    float* y = (float*)d_out;

    // workspace: ~1.05 MB total (round-2 proven safe size)
    char* ws = (char*)d_ws;
    int*   bucket_tok = (int*)ws;             ws += (size_t)EEC*NT*sizeof(int);
    float* bucket_w   = (float*)ws;           ws += (size_t)EEC*NT*sizeof(float);
    int*   counts     = (int*)ws;

    hipMemsetAsync(counts, 0, EEC*sizeof(int), stream);

    routing_kernel<<<NT, 256, 0, stream>>>(hidden, feat, Wr1, br1, Wr2, br2,
                                           Wfe, bfe, Win_h, Win_f, bin_b,
                                           bucket_tok, bucket_w, counts, y);

    dim3 grid2((NT + TM - 1)/TM, EEC);
    expert_mfma<<<grid2, 256, 0, stream>>>(hidden, We1, be1, We2, be2,
                                           bucket_tok, bucket_w, counts, y);
}

// Round 5
// 458.371 us; speedup vs baseline: 2.6543x; 1.0979x over previous
//
#include <hip/hip_runtime.h>
#include <math.h>

// Problem constants (fixed by reference)
#define BB   8
#define LL   512
#define DD   512
#define GG   8
#define SSS  4
#define FGC  4
#define FEC  64
#define EEC  32
#define DHC  256
#define RHC  256
#define NT   (BB*LL)   // 4096 tokens
#define TM   32        // tokens per expert-GEMM tile
#define T8   8         // tokens per routing block

#define XC_STRIDE 264  // shorts per k8 group in Xc (32*8 + 8 pad)
#define HP_STRIDE 272  // shorts per h8 group in Hp (32*8 + 16 pad)

typedef __attribute__((ext_vector_type(8))) short short8;
typedef __attribute__((ext_vector_type(4))) float floatx4;

__device__ __forceinline__ float gelu_exact(float x) {
    return 0.5f * x * (1.0f + erff(x * 0.70710678118654752440f));
}

__device__ __forceinline__ short bf16_rne(float f) {
    union { float f; unsigned u; } a; a.f = f;
    unsigned u = a.u;
    return (short)((u + 0x7fffu + ((u >> 16) & 1u)) >> 16);
}

__device__ __forceinline__ floatx4 mfma16(short8 a, short8 b, floatx4 c) {
    return __builtin_amdgcn_mfma_f32_16x16x32_bf16(a, b, c, 0, 0, 0);
}

// ---------------------------------------------------------------------------
// Kernel 1: routing, 8 tokens per block. fp32-exact topk (same per-token
// selection code as the passing rounds). One weight load now feeds 8 FMAs.
// ---------------------------------------------------------------------------
__global__ __launch_bounds__(256) void routing_kernel(
    const float* __restrict__ hidden, const float* __restrict__ feat,
    const float* __restrict__ Wr1, const float* __restrict__ br1,
    const float* __restrict__ Wr2, const float* __restrict__ br2,
    const float* __restrict__ Wfe, const float* __restrict__ bfe,
    const float* __restrict__ Win_h, const float* __restrict__ Win_f,
    const float* __restrict__ bin_b,
    int* __restrict__ bucket_tok, float* __restrict__ bucket_w,
    int* __restrict__ counts,
    float* __restrict__ y)
{
    const int t0  = blockIdx.x * T8;
    const int tid = threadIdx.x;

    __shared__ float hsb[T8][DD];        // 16 KB
    __shared__ float ghb[T8][RHC];       // 8 KB
    __shared__ float fembb[T8][GG*FEC];  // 16 KB
    __shared__ float featb[T8][GG*FGC];  // 1 KB
    __shared__ float part[256];
    __shared__ float glogb[T8][GG];
    __shared__ float gwvb[T8][GG];
    __shared__ float scoreb[T8][GG];
    __shared__ float ilogb[T8][GG*SSS];
    __shared__ float cwvb[T8][GG*SSS];

    // load hidden rows + zero y rows (d_out is poisoned)
    for (int i = tid; i < T8*DD; i += 256) {
        int r = i >> 9, c = i & 511;
        hsb[r][c] = hidden[(size_t)(t0 + r)*DD + c];
        y[(size_t)(t0 + r)*DD + c] = 0.0f;
    }
    if (tid < T8*GG*FGC) {
        int r = tid >> 5, c = tid & 31;
        featb[r][c] = feat[(t0 + r)*(GG*FGC) + c];
    }
    __syncthreads();

    // gh: thread owns column h=tid for all 8 tokens
    {
        float a0 = br1[tid], a1 = a0, a2 = a0, a3 = a0, a4 = a0, a5 = a0, a6 = a0, a7 = a0;
        const float* w = Wr1 + tid;
        #pragma unroll 4
        for (int d = 0; d < DD; ++d) {
            float wv = w[(size_t)d*RHC];
            a0 += hsb[0][d]*wv; a1 += hsb[1][d]*wv;
            a2 += hsb[2][d]*wv; a3 += hsb[3][d]*wv;
            a4 += hsb[4][d]*wv; a5 += hsb[5][d]*wv;
            a6 += hsb[6][d]*wv; a7 += hsb[7][d]*wv;
        }
        ghb[0][tid] = gelu_exact(a0); ghb[1][tid] = gelu_exact(a1);
        ghb[2][tid] = gelu_exact(a2); ghb[3][tid] = gelu_exact(a3);
        ghb[4][tid] = gelu_exact(a4); ghb[5][tid] = gelu_exact(a5);
        ghb[6][tid] = gelu_exact(a6); ghb[7][tid] = gelu_exact(a7);
    }

    // femb: thread owns 2 (g,e) columns for all 8 tokens
    #pragma unroll
    for (int half = 0; half < 2; ++half) {
        int col = tid + half*256;           // g*64+e
        int g = col >> 6, e = col & 63;
        float w0 = Wfe[(g*FGC+0)*FEC + e];
        float w1 = Wfe[(g*FGC+1)*FEC + e];
        float w2 = Wfe[(g*FGC+2)*FEC + e];
        float w3 = Wfe[(g*FGC+3)*FEC + e];
        float bb = bfe[g*FEC + e];
        #pragma unroll
        for (int r = 0; r < T8; ++r) {
            fembb[r][col] = bb + featb[r][g*4]*w0 + featb[r][g*4+1]*w1
                               + featb[r][g*4+2]*w2 + featb[r][g*4+3]*w3;
        }
    }

    // score per (t,g)
    if (tid < T8*GG) {
        int r = tid >> 3, g = tid & 7;
        float s = 0.f;
        #pragma unroll
        for (int f = 0; f < FGC; ++f) s += fminf(fmaxf(featb[r][g*4+f], 0.f), 1.f);
        scoreb[r][g] = s * 0.25f;
    }
    __syncthreads();

    // glog partials: 64 (t,g) pairs x 4 sub-lanes
    {
        int pair = tid >> 2, sub = tid & 3;
        int t = pair >> 3, g = pair & 7;
        float p = 0.f;
        for (int rr = sub; rr < RHC; rr += 4) p += ghb[t][rr] * Wr2[rr*GG + g];
        part[tid] = p;
    }
    __syncthreads();
    if (tid < T8*GG) {
        int t = tid >> 3, g = tid & 7;
        glogb[t][g] = br2[g] + part[tid*4+0] + part[tid*4+1] + part[tid*4+2] + part[tid*4+3];
    }

    // ilog: thread owns one (t, g, s)
    {
        int t = tid >> 5, gs = tid & 31;
        int g = gs >> 2, s = gs & 3;
        const float* wh = Win_h + (size_t)g*DD*SSS + s;
        float acc = 0.f;
        #pragma unroll 4
        for (int d = 0; d < DD; ++d) acc += hsb[t][d] * wh[d*SSS];
        const float* wf = Win_f + (size_t)g*FEC*SSS + s;
        const float* fe = &fembb[t][g*FEC];
        #pragma unroll 4
        for (int e = 0; e < FEC; ++e) acc += fe[e] * wf[e*SSS];
        const float centers[4] = {0.0f, 1.0f/3.0f, 2.0f/3.0f, 1.0f};
        float diff = scoreb[t][g] - centers[s];
        ilogb[t][gs] = acc + bin_b[gs] - 16.0f * diff * diff;
    }
    __syncthreads();

    // group top-2 softmax per token (identical algorithm to passing rounds)
    if (tid < T8) {
        int t = tid;
        float a = -INFINITY, b = -INFINITY;
        #pragma unroll
        for (int g = 0; g < GG; ++g) {
            float v = glogb[t][g];
            if (v > a) { b = a; a = v; } else if (v > b) { b = v; }
        }
        float thresh = b, m = a, sum = 0.f;
        float ex[GG];
        #pragma unroll
        for (int g = 0; g < GG; ++g) {
            float v = glogb[t][g];
            ex[g] = (v >= thresh) ? __expf(v - m) : 0.f;
            sum += ex[g];
        }
        float inv = 1.0f / sum;
        #pragma unroll
        for (int g = 0; g < GG; ++g) gwvb[t][g] = ex[g] * inv;
    }
    // stage top-2 softmax per (t,g)
    if (tid < T8*GG) {
        int t = tid >> 3, g = tid & 7;
        float vv[4] = {ilogb[t][g*4+0], ilogb[t][g*4+1], ilogb[t][g*4+2], ilogb[t][g*4+3]};
        float a = -INFINITY, b = -INFINITY;
        #pragma unroll
        for (int s = 0; s < 4; ++s) {
            float v = vv[s];
            if (v > a) { b = a; a = v; } else if (v > b) { b = v; }
        }
        float thresh = b, m = a, sum = 0.f;
        float ex[4];
        #pragma unroll
        for (int s = 0; s < 4; ++s) {
            ex[s] = (vv[s] >= thresh) ? __expf(vv[s] - m) : 0.f;
            sum += ex[s];
        }
        float inv = 1.0f / sum;
        #pragma unroll
        for (int s = 0; s < 4; ++s) cwvb[t][g*4 + s] = ex[s] * inv;
    }
    __syncthreads();

    // append to buckets: one thread per token
    if (tid < T8) {
        int t = tid;
        for (int g = 0; g < GG; ++g) {
            float gw = gwvb[t][g];
            if (gw > 0.f) {
                for (int s = 0; s < SSS; ++s) {
                    float w = gw * cwvb[t][g*4 + s];
                    if (w > 0.f) {
                        int ee = g*SSS + s;
                        int pos = atomicAdd(&counts[ee], 1);
                        bucket_tok[ee*NT + pos] = t0 + t;
                        bucket_w[ee*NT + pos]   = w;
                    }
                }
            }
        }
    }
}

// ---------------------------------------------------------------------------
// Kernel 2: bf16 MFMA expert GEMM, B-fragments loaded global->register
// (no W LDS staging: each B element is consumed by exactly one lane).
// Block = (expert, 32-token tile), 4 waves. LDS ~22 KB -> high occupancy.
// A-frag: m=lane&15, k=quad*8+j  (LDS [k8][m][8])
// B-frag: n=lane&15, k=quad*8+j  (8 strided fp32 loads + cvt)
// C/D:    col=lane&15, row=quad*4+reg
// ---------------------------------------------------------------------------
__global__ __launch_bounds__(256) void expert_mfma(
    const float* __restrict__ hidden,
    const float* __restrict__ We1, const float* __restrict__ be1,
    const float* __restrict__ We2, const float* __restrict__ be2,
    const int* __restrict__ bucket_tok, const float* __restrict__ bucket_w,
    const int* __restrict__ counts,
    float* __restrict__ y)
{
    const int e   = blockIdx.y;
    const int cnt = counts[e];
    const int r0  = blockIdx.x * TM;
    if (r0 >= cnt) return;
    const int nrow = min(TM, cnt - r0);
    const int tid  = threadIdx.x;
    const int wave = tid >> 6;
    const int lane = tid & 63;
    const int lm   = lane & 15;
    const int quad = lane >> 4;

    __shared__ short Xc[8 * XC_STRIDE];    // X chunk (64 k), [k8 local][m][8]
    __shared__ short Hp[32 * HP_STRIDE];   // H, [h8][m][8]
    __shared__ int   toks[TM];
    __shared__ float tws[TM];

    if (tid < TM) {
        if (tid < nrow) {
            toks[tid] = bucket_tok[e*NT + r0 + tid];
            tws[tid]  = bucket_w[e*NT + r0 + tid];
        } else { toks[tid] = -1; tws[tid] = 0.f; }
    }
    __syncthreads();

    // ---- phase 1: H = gelu(X @ We1 + be1); wave owns 32x64 of 32x256 ----
    floatx4 acc[2][4];
    #pragma unroll
    for (int mb = 0; mb < 2; ++mb)
        #pragma unroll
        for (int nb = 0; nb < 4; ++nb)
            acc[mb][nb] = (floatx4){0.f, 0.f, 0.f, 0.f};

    const float* W1 = We1 + (size_t)e * DD * DHC;    // [k][n], n stride DHC
    const int xr = tid & 31;     // token row for X staging
    const int xc = tid >> 5;     // k8 group 0..7

    for (int kc = 0; kc < DD; kc += 64) {
        __syncthreads();   // protect Xc from previous iteration's reads
        {
            const int tk = toks[xr];
            float4 v0 = make_float4(0.f,0.f,0.f,0.f), v1 = v0;
            if (tk >= 0) {
                const float* src = hidden + (size_t)tk*DD + kc + xc*8;
                v0 = *(const float4*)src;
                v1 = *(const float4*)(src + 4);
            }
            short8 xv;
            xv[0]=bf16_rne(v0.x); xv[1]=bf16_rne(v0.y); xv[2]=bf16_rne(v0.z); xv[3]=bf16_rne(v0.w);
            xv[4]=bf16_rne(v1.x); xv[5]=bf16_rne(v1.y); xv[6]=bf16_rne(v1.z); xv[7]=bf16_rne(v1.w);
            *(short8*)(&Xc[xc * XC_STRIDE + xr * 8]) = xv;
        }
        __syncthreads();
        #pragma unroll
        for (int kk = 0; kk < 64; kk += 32) {
            const int k8l = (kk >> 3) + quad;
            short8 a0 = *(const short8*)(&Xc[k8l * XC_STRIDE + lm * 8]);
            short8 a1 = *(const short8*)(&Xc[k8l * XC_STRIDE + (16 + lm) * 8]);
            const int k0 = kc + k8l*8;      // global k of j=0
            #pragma unroll
            for (int nb = 0; nb < 4; ++nb) {
                const int n = wave*64 + nb*16 + lm;
                const float* src = W1 + (size_t)k0*DHC + n;
                short8 b;
                #pragma unroll
                for (int j = 0; j < 8; ++j) b[j] = bf16_rne(src[(size_t)j*DHC]);
                acc[0][nb] = mfma16(a0, b, acc[0][nb]);
                acc[1][nb] = mfma16(a1, b, acc[1][nb]);
            }
        }
    }

    // bias + gelu -> Hp (bf16, A-layout for phase 2); waves write disjoint h
    __syncthreads();   // all Xc reads done; Hp aliasing not an issue but keep order
    #pragma unroll
    for (int nb = 0; nb < 4; ++nb) {
        const int h = wave*64 + nb*16 + lm;
        const float b1 = be1[e*DHC + h];
        #pragma unroll
        for (int mb = 0; mb < 2; ++mb) {
            #pragma unroll
            for (int r = 0; r < 4; ++r) {
                const int m = mb*16 + quad*4 + r;
                Hp[(h >> 3) * HP_STRIDE + m * 8 + (h & 7)] =
                    bf16_rne(gelu_exact(acc[mb][nb][r] + b1));
            }
        }
    }
    __syncthreads();

    // ---- phase 2: Y += w*(H @ We2 + be2); wave owns 32x128 of 32x512 ----
    floatx4 c[2][8];
    #pragma unroll
    for (int mb = 0; mb < 2; ++mb)
        #pragma unroll
        for (int nb = 0; nb < 8; ++nb)
            c[mb][nb] = (floatx4){0.f, 0.f, 0.f, 0.f};

    const float* W2 = We2 + (size_t)e * DHC * DD;    // [k][n], n stride DD

    for (int kc = 0; kc < DHC; kc += 32) {
        const int k8 = (kc >> 3) + quad;
        short8 a0 = *(const short8*)(&Hp[k8 * HP_STRIDE + lm * 8]);
        short8 a1 = *(const short8*)(&Hp[k8 * HP_STRIDE + (16 + lm) * 8]);
        const int k0 = k8*8;
        #pragma unroll
        for (int nb = 0; nb < 8; ++nb) {
            const int n = wave*128 + nb*16 + lm;
            const float* src = W2 + (size_t)k0*DD + n;
            short8 b;
            #pragma unroll
            for (int j = 0; j < 8; ++j) b[j] = bf16_rne(src[(size_t)j*DD]);
            c[0][nb] = mfma16(a0, b, c[0][nb]);
            c[1][nb] = mfma16(a1, b, c[1][nb]);
        }
    }

    // epilogue: weighted atomicAdd into y (+ be2)
    #pragma unroll
    for (int nb = 0; nb < 8; ++nb) {
        const int col = wave*128 + nb*16 + lm;
        const float b2 = be2[e*DD + col];
        #pragma unroll
        for (int mb = 0; mb < 2; ++mb) {
            #pragma unroll
            for (int r = 0; r < 4; ++r) {
                const int m = mb*16 + quad*4 + r;
                const int tk = toks[m];
                if (tk >= 0)
                    atomicAdd(&y[(size_t)tk*DD + col], tws[m] * (c[mb][nb][r] + b2));
            }
        }
    }
}

extern "C" void kernel_launch(void* const* d_in, const int* in_sizes, int n_in,
                              void* d_out, int out_size, void* d_ws, size_t ws_size,
                              hipStream_t stream) {
    const float* hidden = (const float*)d_in[0];
    const float* feat   = (const float*)d_in[1];
    // d_in[2] = valid_mask (unused)
    const float* Wr1    = (const float*)d_in[3];
    const float* br1    = (const float*)d_in[4];
    const float* Wr2    = (const float*)d_in[5];
    const float* br2    = (const float*)d_in[6];
    const float* Wfe    = (const float*)d_in[7];
    const float* bfe    = (const float*)d_in[8];
    const float* Win_h  = (const float*)d_in[9];
    const float* Win_f  = (const float*)d_in[10];
    const float* bin_b  = (const float*)d_in[11];
    const float* We1    = (const float*)d_in[12];
    const float* be1    = (const float*)d_in[13];
    const float* We2    = (const float*)d_in[14];
    const float* be2    = (const float*)d_in[15];
    float* y = (float*)d_out;

    // workspace: ~1.05 MB total (proven safe size)
    char* ws = (char*)d_ws;
    int*   bucket_tok = (int*)ws;             ws += (size_t)EEC*NT*sizeof(int);
    float* bucket_w   = (float*)ws;           ws += (size_t)EEC*NT*sizeof(float);
    int*   counts     = (int*)ws;

    hipMemsetAsync(counts, 0, EEC*sizeof(int), stream);

    routing_kernel<<<NT/T8, 256, 0, stream>>>(hidden, feat, Wr1, br1, Wr2, br2,
                                              Wfe, bfe, Win_h, Win_f, bin_b,
                                              bucket_tok, bucket_w, counts, y);

    dim3 grid2((NT + TM - 1)/TM, EEC);
    expert_mfma<<<grid2, 256, 0, stream>>>(hidden, We1, be1, We2, be2,
                                           bucket_tok, bucket_w, counts, y);
}